// Round 13
// baseline (27626.279 us; speedup 1.0000x reference)
//
#include <hip/hip_runtime.h>

typedef unsigned int u32;
typedef unsigned long long u64;
typedef unsigned short u16;
typedef __attribute__((ext_vector_type(8))) short bf16x8;
typedef __attribute__((ext_vector_type(4))) float f32x4;
typedef __attribute__((ext_vector_type(4))) u32 u32x4;

static constexpr int NWG    = 256;   // 16 groups x 16 h-slices
static constexpr int NTHR   = 512;   // 8 waves -> 2 waves/SIMD at 1 WG/CU
static constexpr int NSTEPS = 511;

// ---- workspace layout (bytes) ----
// kg: u32 kg[6][16][16][8][8]  (stage, group, slice, rowpair, h_local) tagged bf16x2
//     each u32 = k for rows (2*rp, 2*rp+1) at h = slice*8 + h_local
static constexpr size_t K_OFF   = 0;
static constexpr size_t KG_U32  = 6ull * 16 * 16 * 64;           // 98304
static constexpr size_t W0_OFF  = KG_U32 * 4;                    // 393216
static constexpr size_t W1_OFF  = W0_OFF + 256 * 128 * 2;
static constexpr size_t W2_OFF  = W1_OFF + 256 * 256 * 2;
static constexpr size_t WS_NEED = W2_OFF + 4096ull * 256 * 2;

// ---- Tsit5 tableau (constexpr: folds to immediates in the unrolled stage loop) ----
static constexpr float AT6c[6][6] = {
  {0.f, 0.f, 0.f, 0.f, 0.f, 0.f},
  {0.161f, 0.f, 0.f, 0.f, 0.f, 0.f},
  {-0.008480655492356989f, 0.335480655492357f, 0.f, 0.f, 0.f, 0.f},
  {2.8971530571054935f, -6.359448489975075f, 4.3622954328695815f, 0.f, 0.f, 0.f},
  {5.325864828439257f, -11.748883564062828f, 7.4955393428898365f, -0.09249506636175525f, 0.f, 0.f},
  {5.86145544294642f, -12.92096931784711f, 8.159367898576159f, -0.071584973281401f, -0.028269050394068383f, 0.f}
};
static constexpr float BT6c[6] = {
  0.09646076681806523f, 0.01f, 0.4798896504144996f, 1.379008574103742f,
  -3.290069515436081f, 2.324710524099774f
};
static constexpr float CT6c[6] = {0.f, 0.161f, 0.327f, 0.9f, 0.9800255409045097f, 1.f};

__device__ __forceinline__ u16 cvbf(float f) {
  u32 u = __float_as_uint(f);
  return (u16)((u + 0x7fffu + ((u >> 16) & 1u)) >> 16);
}
__device__ __forceinline__ u32 cvt_pk(float lo, float hi) {  // packed bf16 pair, RNE
  u32 r;
  asm("v_cvt_pk_bf16_f32 %0, %1, %2" : "=v"(r) : "v"(lo), "v"(hi));
  return r;
}
__device__ __forceinline__ float blo(u32 u) { return __uint_as_float(u << 16); }
__device__ __forceinline__ float bhi(u32 u) { return __uint_as_float(u & 0xffff0000u); }
__device__ __forceinline__ float frcp(float x) { return __builtin_amdgcn_rcpf(x); }
__device__ __forceinline__ float fsilu(float x) { return x * frcp(1.f + __expf(-x)); }
__device__ __forceinline__ float ftanh(float x) { return 1.f - 2.f * frcp(__expf(2.f * x) + 1.f); }
__device__ __forceinline__ f32x4 MF(bf16x8 a, bf16x8 b, f32x4 c) {
  return __builtin_amdgcn_mfma_f32_16x16x32_bf16(a, b, c, 0, 0, 0);
}

__global__ void cvt_weights(const float* __restrict__ w0, const float* __restrict__ w1,
                            const float* __restrict__ w2, u16* __restrict__ o0,
                            u16* __restrict__ o1, u16* __restrict__ o2) {
  int i = blockIdx.x * blockDim.x + threadIdx.x;
  if (i < 256 * 128)  o0[i] = cvbf(w0[i]);
  if (i < 256 * 256)  o1[i] = cvbf(w1[i]);
  if (i < 4096 * 256) o2[i] = cvbf(w2[i]);
}

// Persistent MFMA kernel, 8 waves/WG. WG = (group g: 16 rows) x (h-slice hs: 256 cols).
// Wave w owns cols [w*32, w*32+32): 2 ct tiles front, h_local = w in GEMM3.
// W0/W1 frags in regs; W2 slice in LDS. Exchange: single-hop tagged slab, direct
// per-lane store after reduce (no LDS hop, no 4th barrier); dxt double-buffered.
__launch_bounds__(NTHR)
__global__ void cde_kernel(const float* __restrict__ ts,
                           const float* __restrict__ cdg, const float* __restrict__ ccg,
                           const float* __restrict__ cbg,
                           const float* __restrict__ x0g, const float* __restrict__ l1w,
                           const float* __restrict__ l1b,
                           const float* __restrict__ b0g, const float* __restrict__ b1g,
                           const float* __restrict__ b2g,
                           const float* __restrict__ l2w, const float* __restrict__ l2b,
                           const u16* __restrict__ w0b, const u16* __restrict__ w1b,
                           const u16* __restrict__ w2b,
                           u32* kg, float* __restrict__ outp) {
  __shared__ u32 w2l[32768];        // 128KB W2 frags [ks(8)][gct(16)][lane(64)][4 u32]
  __shared__ u16 ysl[16 * 128];     // 4KB  swizzled
  __shared__ u16 h1l[16 * 256];     // 8KB  swizzled
  __shared__ u16 h2l[16 * 256];     // 8KB  swizzled
  __shared__ float dxt2[2][32 * 17];// dX [d][row], double-buffered by stage parity
  __shared__ float lg[192];

  const int t  = threadIdx.x;
  const int wg = blockIdx.x;
  const int g  = wg >> 4;
  const int hs = wg & 15;
  const int b0r = g * 16;
  const int w = t >> 6, l = t & 63, lr = l & 15, lk = l >> 4;
  const int row_o = t & 15;
  const int hb    = ((t >> 4) & 15) * 8;
  const bool act  = (t < 256);     // waves 0-3: state-owning threads
  const int  rp   = row_o & 1;     // row parity (u32 half select)

  // ---- persistent weight fragments (wave w: cols w*32 + ct*16 + lr, ct in {0,1}) ----
  bf16x8 w0f[2][4], w1f[2][8];
  float bias0v[2], bias1v[2], bias2v[2];
#pragma unroll
  for (int ct = 0; ct < 2; ++ct) {
    const int col = w * 32 + ct * 16 + lr;
    bias0v[ct] = b0g[col];
    bias1v[ct] = b1g[col];
    bias2v[ct] = b2g[hs * 256 + col];
    const u16* base0 = w0b + (size_t)col * 128 + lk * 8;
#pragma unroll
    for (int ks = 0; ks < 4; ++ks) w0f[ct][ks] = *(const bf16x8*)(base0 + ks * 32);
    const u16* base1 = w1b + (size_t)col * 256 + lk * 8;
#pragma unroll
    for (int ks = 0; ks < 8; ++ks) w1f[ct][ks] = *(const bf16x8*)(base1 + ks * 32);
    const u16* base2 = w2b + (size_t)(hs * 256 + col) * 256 + lk * 8;
#pragma unroll
    for (int ks = 0; ks < 8; ++ks) {
      u32x4 v = *(const u32x4*)(base2 + ks * 32);
      *(u32x4*)&w2l[(size_t)((ks * 16 + (w * 2 + ct)) * 64 + l) * 4] = v;
    }
  }

  // ---- y0 (valid for act threads; duplicates elsewhere, never stored) ----
  float yv[8];
  {
    const float* xr = x0g + (size_t)(b0r + row_o) * 32;
#pragma unroll
    for (int e = 0; e < 8; ++e) {
      float acc = l1b[hb + e];
      const float* wr = l1w + (size_t)(hb + e) * 32;
#pragma unroll
      for (int d = 0; d < 32; ++d) acc = fmaf(xr[d], wr[d], acc);
      yv[e] = acc;
    }
  }

  u32 kk[6][4];
#pragma unroll
  for (int j = 0; j < 6; ++j)
#pragma unroll
    for (int p = 0; p < 4; ++p) kk[j][p] = 0u;

  float pcb[2], pcc[2], pcd[2];
  auto ld_coeff = [&](int st) {
    if (!act) return;
    size_t gi = ((size_t)(b0r + (t >> 4)) * 511 + st) * 32 + 2 * (t & 15);
    float2 vb = *(const float2*)(cbg + gi); pcb[0] = vb.x; pcb[1] = vb.y;
    float2 vc = *(const float2*)(ccg + gi); pcc[0] = vc.x; pcc[1] = vc.y;
    float2 vd = *(const float2*)(cdg + gi); pcd[0] = vd.x; pcd[1] = vd.y;
  };
  pcb[0]=pcb[1]=pcc[0]=pcc[1]=pcd[0]=pcd[1]=0.f;
  ld_coeff(0);
  float hh_next = ts[1] - ts[0];
  // act thread's 32B of each (stage,group) slab: slice=t>>4, rowpair=row_o>>1
  const size_t myoff = (size_t)((t >> 4) * 64 + (row_o >> 1) * 8);
  __syncthreads();

#pragma unroll 1
  for (int step = 0; step < NSTEPS; ++step) {
    const float hh = hh_next;
    const float cb0 = pcb[0], cb1 = pcb[1];
    const float cc0 = pcc[0], cc1 = pcc[1];
    const float cd0 = pcd[0], cd1 = pcd[1];
    if (step + 1 < NSTEPS) { ld_coeff(step + 1); hh_next = ts[step + 2] - ts[step + 1]; }
    const u32 tg = (u32)(step + 1) & 3u;              // per-step sequence tag
    const u32 tgins = (tg & 1u) | ((tg & 2u) << 15);  // bit0 + bit16

    // act threads spin until all 8 tagged words (their 2 rows x 8 h) arrive
    auto spin_gather = [&](int sdone, u32 (&kks)[4]) {
      if (!act) return;
      const u64* p = (const u64*)(kg + (size_t)((sdone * 16 + g) * 16) * 64 + myoff);
      u64 a, b, c, d;
      for (;;) {
        a = __hip_atomic_load(p,     __ATOMIC_RELAXED, __HIP_MEMORY_SCOPE_AGENT);
        b = __hip_atomic_load(p + 1, __ATOMIC_RELAXED, __HIP_MEMORY_SCOPE_AGENT);
        c = __hip_atomic_load(p + 2, __ATOMIC_RELAXED, __HIP_MEMORY_SCOPE_AGENT);
        d = __hip_atomic_load(p + 3, __ATOMIC_RELAXED, __HIP_MEMORY_SCOPE_AGENT);
        u32 bad = 0;
        u32 x0 = (u32)a, x1 = (u32)(a >> 32), x2 = (u32)b, x3 = (u32)(b >> 32);
        u32 x4 = (u32)c, x5 = (u32)(c >> 32), x6 = (u32)d, x7 = (u32)(d >> 32);
        bad |= ((x0 & 1u) | ((x0 >> 15) & 2u)) ^ tg;
        bad |= ((x1 & 1u) | ((x1 >> 15) & 2u)) ^ tg;
        bad |= ((x2 & 1u) | ((x2 >> 15) & 2u)) ^ tg;
        bad |= ((x3 & 1u) | ((x3 >> 15) & 2u)) ^ tg;
        bad |= ((x4 & 1u) | ((x4 >> 15) & 2u)) ^ tg;
        bad |= ((x5 & 1u) | ((x5 >> 15) & 2u)) ^ tg;
        bad |= ((x6 & 1u) | ((x6 >> 15) & 2u)) ^ tg;
        bad |= ((x7 & 1u) | ((x7 >> 15) & 2u)) ^ tg;
        if (bad == 0u) {
          // repack: kks[p] = (h=2p for my row, h=2p+1 for my row)
          if (rp) {
            kks[0] = (x0 >> 16) | (x1 & 0xFFFF0000u);
            kks[1] = (x2 >> 16) | (x3 & 0xFFFF0000u);
            kks[2] = (x4 >> 16) | (x5 & 0xFFFF0000u);
            kks[3] = (x6 >> 16) | (x7 & 0xFFFF0000u);
          } else {
            kks[0] = (x0 & 0xFFFFu) | (x1 << 16);
            kks[1] = (x2 & 0xFFFFu) | (x3 << 16);
            kks[2] = (x4 & 0xFFFFu) | (x5 << 16);
            kks[3] = (x6 & 0xFFFFu) | (x7 << 16);
          }
          break;
        }
      }
    };

#pragma unroll
    for (int s = 0; s < 6; ++s) {
      // ---- pre-spin: dxt(s) [parity buffer] + k-independent ys terms (j <= s-2) ----
      float v0p[4], v1p[4];
      if (act) {
        float* dx = dxt2[s & 1];
        const float fr = CT6c[s] * hh;
        int d0 = 2 * (t & 15), rl = t >> 4;
        dx[d0 * 17 + rl]       = cb0 + fr * (2.f * cc0 + 3.f * fr * cd0);
        dx[(d0 + 1) * 17 + rl] = cb1 + fr * (2.f * cc1 + 3.f * fr * cd1);
#pragma unroll
        for (int p = 0; p < 4; ++p) { v0p[p] = yv[2 * p]; v1p[p] = yv[2 * p + 1]; }
        for (int j = 0; j + 1 < s; ++j) {
          const float aj = hh * AT6c[s][j];
#pragma unroll
          for (int p = 0; p < 4; ++p) {
            v0p[p] = fmaf(aj, blo(kk[j][p]), v0p[p]);
            v1p[p] = fmaf(aj, bhi(kk[j][p]), v1p[p]);
          }
        }
      }
      if (s > 0) spin_gather(s - 1, kk[s - 1]);
      if (act) {
        if (s > 0) {
          const float al = hh * AT6c[s][s - 1];
#pragma unroll
          for (int p = 0; p < 4; ++p) {
            v0p[p] = fmaf(al, blo(kk[s - 1][p]), v0p[p]);
            v1p[p] = fmaf(al, bhi(kk[s - 1][p]), v1p[p]);
          }
        }
        u32 yp[4];
#pragma unroll
        for (int p = 0; p < 4; ++p) yp[p] = cvt_pk(v0p[p], v1p[p]);
        int boff = row_o * 256 + ((((t >> 4) & 15) * 16) ^ ((row_o & 7) << 4));
        u32x4 wv_; wv_[0] = yp[0]; wv_[1] = yp[1]; wv_[2] = yp[2]; wv_[3] = yp[3];
        *(u32x4*)((char*)ysl + boff) = wv_;
      }
      __syncthreads();

      // GEMM1 (per wave: 2 ct tiles)
      f32x4 acc[2];
#pragma unroll
      for (int ct = 0; ct < 2; ++ct) acc[ct] = f32x4{0.f, 0.f, 0.f, 0.f};
#pragma unroll
      for (int ks = 0; ks < 4; ++ks) {
        bf16x8 af = *(const bf16x8*)((char*)ysl + lr * 256 + ((ks * 64 + lk * 16) ^ ((lr & 7) << 4)));
#pragma unroll
        for (int ct = 0; ct < 2; ++ct) acc[ct] = MF(af, w0f[ct][ks], acc[ct]);
      }
#pragma unroll
      for (int ct = 0; ct < 2; ++ct) {
        int col2 = (w * 32 + ct * 16 + lr) * 2;
        int r0 = lk * 4;
        u32 p01 = cvt_pk(fsilu(acc[ct][0] + bias0v[ct]), fsilu(acc[ct][1] + bias0v[ct]));
        u32 p23 = cvt_pk(fsilu(acc[ct][2] + bias0v[ct]), fsilu(acc[ct][3] + bias0v[ct]));
        *(u16*)((char*)h1l + (r0 + 0) * 512 + (col2 ^ (((r0 + 0) & 7) << 4))) = (u16)p01;
        *(u16*)((char*)h1l + (r0 + 1) * 512 + (col2 ^ (((r0 + 1) & 7) << 4))) = (u16)(p01 >> 16);
        *(u16*)((char*)h1l + (r0 + 2) * 512 + (col2 ^ (((r0 + 2) & 7) << 4))) = (u16)p23;
        *(u16*)((char*)h1l + (r0 + 3) * 512 + (col2 ^ (((r0 + 3) & 7) << 4))) = (u16)(p23 >> 16);
      }
      __syncthreads();

      // GEMM2
#pragma unroll
      for (int ct = 0; ct < 2; ++ct) acc[ct] = f32x4{0.f, 0.f, 0.f, 0.f};
#pragma unroll
      for (int ks = 0; ks < 8; ++ks) {
        bf16x8 af = *(const bf16x8*)((char*)h1l + lr * 512 + ((ks * 64 + lk * 16) ^ ((lr & 7) << 4)));
#pragma unroll
        for (int ct = 0; ct < 2; ++ct) acc[ct] = MF(af, w1f[ct][ks], acc[ct]);
      }
#pragma unroll
      for (int ct = 0; ct < 2; ++ct) {
        int col2 = (w * 32 + ct * 16 + lr) * 2;
        int r0 = lk * 4;
        u32 p01 = cvt_pk(fsilu(acc[ct][0] + bias1v[ct]), fsilu(acc[ct][1] + bias1v[ct]));
        u32 p23 = cvt_pk(fsilu(acc[ct][2] + bias1v[ct]), fsilu(acc[ct][3] + bias1v[ct]));
        *(u16*)((char*)h2l + (r0 + 0) * 512 + (col2 ^ (((r0 + 0) & 7) << 4))) = (u16)p01;
        *(u16*)((char*)h2l + (r0 + 1) * 512 + (col2 ^ (((r0 + 1) & 7) << 4))) = (u16)(p01 >> 16);
        *(u16*)((char*)h2l + (r0 + 2) * 512 + (col2 ^ (((r0 + 2) & 7) << 4))) = (u16)p23;
        *(u16*)((char*)h2l + (r0 + 3) * 512 + (col2 ^ (((r0 + 3) & 7) << 4))) = (u16)(p23 >> 16);
      }
      __syncthreads();

      // GEMM3 (gct = w*2+ct) + tanh + dX contract; wave w produces h_local = w
#pragma unroll
      for (int ct = 0; ct < 2; ++ct) acc[ct] = f32x4{0.f, 0.f, 0.f, 0.f};
#pragma unroll
      for (int ks = 0; ks < 8; ++ks) {
        bf16x8 af = *(const bf16x8*)((char*)h2l + lr * 512 + ((ks * 64 + lk * 16) ^ ((lr & 7) << 4)));
#pragma unroll
        for (int ct = 0; ct < 2; ++ct) {
          bf16x8 bf = *(const bf16x8*)&w2l[(size_t)((ks * 16 + (w * 2 + ct)) * 64 + l) * 4];
          acc[ct] = MF(af, bf, acc[ct]);
        }
      }
      {
        const float* dx = dxt2[s & 1];
        float sv[4];
#pragma unroll
        for (int r = 0; r < 4; ++r) {
          int row = lk * 4 + r;
          sv[r] = ftanh(acc[0][r] + bias2v[0]) * dx[lr * 17 + row] +
                  ftanh(acc[1][r] + bias2v[1]) * dx[(16 + lr) * 17 + row];
        }
#pragma unroll
        for (int m = 1; m < 16; m <<= 1) {
#pragma unroll
          for (int r = 0; r < 4; ++r) sv[r] += __shfl_xor(sv[r], m, 64);
        }
        // direct tagged store: lane lk holds rows 4lk..4lk+3 of h_local=w.
        // pack row-pairs in-register, fire to fabric now (no LDS hop, no barrier).
        if (lr == 0) {
          u32 p01 = (cvt_pk(sv[0], sv[1]) & 0xFFFEFFFEu) | tgins;  // rowpair 2lk
          u32 p23 = (cvt_pk(sv[2], sv[3]) & 0xFFFEFFFEu) | tgins;  // rowpair 2lk+1
          u32* dst = kg + (size_t)((s * 16 + g) * 16 + hs) * 64 + (size_t)(lk * 2) * 8 + w;
          __hip_atomic_store(dst,     p01, __ATOMIC_RELAXED, __HIP_MEMORY_SCOPE_AGENT);
          __hip_atomic_store(dst + 8, p23, __ATOMIC_RELAXED, __HIP_MEMORY_SCOPE_AGENT);
        }
      }
      // no barrier here: next stage's pre-spin writes only dxt2[(s+1)&1] (other
      // buffer) and ysl (all G1 reads completed before this stage's 2nd barrier).
    }

    spin_gather(5, kk[5]);

    // y += h * sum_j B[j] k_j (act threads hold real state)
#pragma unroll
    for (int p = 0; p < 4; ++p) {
      float v0 = yv[2 * p], v1 = yv[2 * p + 1];
#pragma unroll
      for (int j = 0; j < 6; ++j) {
        const float cj = hh * BT6c[j];
        v0 = fmaf(cj, blo(kk[j][p]), v0);
        v1 = fmaf(cj, bhi(kk[j][p]), v1);
      }
      yv[2 * p] = v0; yv[2 * p + 1] = v1;
    }
  }  // steps

  // ---- head ----
  __syncthreads();
  if (hs == 0) {
    float* yh = (float*)w2l;
    if (act) {
#pragma unroll
      for (int e = 0; e < 8; ++e) yh[row_o * 132 + hb + e] = yv[e];
    }
    __syncthreads();
    if (t < 160) {
      int r = t / 10, c = t - r * 10;
      float acc = l2b[c];
      const float* wr = l2w + (size_t)c * 128;
      for (int h2 = 0; h2 < 128; ++h2) acc = fmaf(yh[r * 132 + h2], wr[h2], acc);
      lg[r * 12 + c] = acc;
    }
    __syncthreads();
    if (t < 16) {
      float m = lg[t * 12];
#pragma unroll
      for (int c = 1; c < 10; ++c) m = fmaxf(m, lg[t * 12 + c]);
      float sum = 0.f, ex[10];
#pragma unroll
      for (int c = 0; c < 10; ++c) { ex[c] = __expf(lg[t * 12 + c] - m); sum += ex[c]; }
      float inv = 1.f / sum;
#pragma unroll
      for (int c = 0; c < 10; ++c) outp[(size_t)(b0r + t) * 10 + c] = ex[c] * inv;
    }
  }
}

extern "C" void kernel_launch(void* const* d_in, const int* in_sizes, int n_in,
                              void* d_out, int out_size, void* d_ws, size_t ws_size,
                              hipStream_t stream) {
  (void)in_sizes; (void)n_in; (void)out_size;
  if (ws_size < WS_NEED) return;

  const float* ts  = (const float*)d_in[0];
  const float* cd  = (const float*)d_in[1];
  const float* cc  = (const float*)d_in[2];
  const float* cb  = (const float*)d_in[3];
  // d_in[4] = coeff_a (unused by the reference math)
  const float* x0  = (const float*)d_in[5];
  const float* l1w = (const float*)d_in[6];
  const float* l1b = (const float*)d_in[7];
  const float* w0  = (const float*)d_in[8];
  const float* b0  = (const float*)d_in[9];
  const float* w1  = (const float*)d_in[10];
  const float* b1  = (const float*)d_in[11];
  const float* w2  = (const float*)d_in[12];
  const float* b2  = (const float*)d_in[13];
  const float* l2w = (const float*)d_in[14];
  const float* l2b = (const float*)d_in[15];

  char* ws = (char*)d_ws;
  u32* kg  = (u32*)(ws + K_OFF);
  u16* w0b = (u16*)(ws + W0_OFF);
  u16* w1b = (u16*)(ws + W1_OFF);
  u16* w2b = (u16*)(ws + W2_OFF);

  // init kg to tag=3 pattern (0x01010101): never matches any step's expected tag
  // before its first write, on every call (fresh or replayed).
  (void)hipMemsetAsync(kg, 0x01, KG_U32 * 4, stream);
  cvt_weights<<<4096, 256, 0, stream>>>(w0, w1, w2, w0b, w1b, w2b);
  cde_kernel<<<NWG, NTHR, 0, stream>>>(ts, cd, cc, cb, x0, l1w, l1b,
                                       b0, b1, b2, l2w, l2b,
                                       w0b, w1b, w2b, kg, (float*)d_out);
}

// Round 14
// 12181.253 us; speedup vs baseline: 2.2679x; 2.2679x over previous
//
#include <hip/hip_runtime.h>

typedef unsigned int u32;
typedef unsigned long long u64;
typedef unsigned short u16;
typedef __attribute__((ext_vector_type(8))) short bf16x8;
typedef __attribute__((ext_vector_type(4))) float f32x4;
typedef __attribute__((ext_vector_type(4))) u32 u32x4;

static constexpr int NWG    = 256;   // 16 groups x 16 h-slices
static constexpr int NTHR   = 512;   // 8 waves -> 2 waves/SIMD at 1 WG/CU
static constexpr int NSTEPS = 511;

// ---- workspace layout (bytes) ----
// kg: u32 kg[6][16][16][64]  (stage, group, h-slice, row*4+hpair) packed tagged bf16x2
static constexpr size_t K_OFF   = 0;
static constexpr size_t KG_U32  = 6ull * 16 * 16 * 64;           // 98304
static constexpr size_t W0_OFF  = KG_U32 * 4;                    // 393216
static constexpr size_t W1_OFF  = W0_OFF + 256 * 128 * 2;
static constexpr size_t W2_OFF  = W1_OFF + 256 * 256 * 2;
static constexpr size_t WS_NEED = W2_OFF + 4096ull * 256 * 2;

// ---- Tsit5 tableau (constexpr: folds to immediates in the unrolled stage loop) ----
static constexpr float AT6c[6][6] = {
  {0.f, 0.f, 0.f, 0.f, 0.f, 0.f},
  {0.161f, 0.f, 0.f, 0.f, 0.f, 0.f},
  {-0.008480655492356989f, 0.335480655492357f, 0.f, 0.f, 0.f, 0.f},
  {2.8971530571054935f, -6.359448489975075f, 4.3622954328695815f, 0.f, 0.f, 0.f},
  {5.325864828439257f, -11.748883564062828f, 7.4955393428898365f, -0.09249506636175525f, 0.f, 0.f},
  {5.86145544294642f, -12.92096931784711f, 8.159367898576159f, -0.071584973281401f, -0.028269050394068383f, 0.f}
};
static constexpr float BT6c[6] = {
  0.09646076681806523f, 0.01f, 0.4798896504144996f, 1.379008574103742f,
  -3.290069515436081f, 2.324710524099774f
};
static constexpr float CT6c[6] = {0.f, 0.161f, 0.327f, 0.9f, 0.9800255409045097f, 1.f};

__device__ __forceinline__ u16 cvbf(float f) {
  u32 u = __float_as_uint(f);
  return (u16)((u + 0x7fffu + ((u >> 16) & 1u)) >> 16);
}
__device__ __forceinline__ u32 cvt_pk(float lo, float hi) {  // packed bf16 pair, RNE
  u32 r;
  asm("v_cvt_pk_bf16_f32 %0, %1, %2" : "=v"(r) : "v"(lo), "v"(hi));
  return r;
}
__device__ __forceinline__ float blo(u32 u) { return __uint_as_float(u << 16); }
__device__ __forceinline__ float bhi(u32 u) { return __uint_as_float(u & 0xffff0000u); }
__device__ __forceinline__ float frcp(float x) { return __builtin_amdgcn_rcpf(x); }
__device__ __forceinline__ float fsilu(float x) { return x * frcp(1.f + __expf(-x)); }
__device__ __forceinline__ float ftanh(float x) { return 1.f - 2.f * frcp(__expf(2.f * x) + 1.f); }
__device__ __forceinline__ f32x4 MF(bf16x8 a, bf16x8 b, f32x4 c) {
  return __builtin_amdgcn_mfma_f32_16x16x32_bf16(a, b, c, 0, 0, 0);
}

__global__ void cvt_weights(const float* __restrict__ w0, const float* __restrict__ w1,
                            const float* __restrict__ w2, u16* __restrict__ o0,
                            u16* __restrict__ o1, u16* __restrict__ o2) {
  int i = blockIdx.x * blockDim.x + threadIdx.x;
  if (i < 256 * 128)  o0[i] = cvbf(w0[i]);
  if (i < 256 * 256)  o1[i] = cvbf(w1[i]);
  if (i < 4096 * 256) o2[i] = cvbf(w2[i]);
}

// Persistent MFMA kernel, 8 waves/WG. WG = (group g: 16 rows) x (h-slice hs: 256 cols).
// Wave w owns cols [w*32, w*32+32): 2 ct tiles front, 2 gct tiles + h=w in GEMM3.
// W0/W1 fragments VGPR/AGPR-resident; W2 slice in LDS (reg-residence infeasible:
// needs ~290 unified regs/wave > 256 budget at 2 waves/SIMD — R10/R11 spilled).
// Exchange: single-hop tagged slab, coalesced 256B single-writer stores (any
// scatter/de-sync multiplies fabric traffic — R9/R13 regressions).
__launch_bounds__(NTHR)
__global__ void cde_kernel(const float* __restrict__ ts,
                           const float* __restrict__ cdg, const float* __restrict__ ccg,
                           const float* __restrict__ cbg,
                           const float* __restrict__ x0g, const float* __restrict__ l1w,
                           const float* __restrict__ l1b,
                           const float* __restrict__ b0g, const float* __restrict__ b1g,
                           const float* __restrict__ b2g,
                           const float* __restrict__ l2w, const float* __restrict__ l2b,
                           const u16* __restrict__ w0b, const u16* __restrict__ w1b,
                           const u16* __restrict__ w2b,
                           u32* kg, float* __restrict__ outp) {
  __shared__ u32 w2l[32768];      // 128KB W2 frags [ks(8)][gct(16)][lane(64)][4 u32]
  __shared__ u16 ysl[16 * 128];   // 4KB  swizzled
  __shared__ u16 h1l[16 * 256];   // 8KB  swizzled
  __shared__ u16 h2l[16 * 256];   // 8KB  swizzled
  __shared__ float dxt[32 * 17];  // dX [d][row]
  __shared__ float lg[192];
  __shared__ u32 kexw[64];        // k assembly: [row(16)][hpair(4)], u16 halves by h

  const int t  = threadIdx.x;
  const int wg = blockIdx.x;
  const int g  = wg >> 4;
  const int hs = wg & 15;
  const int b0r = g * 16;
  const int w = t >> 6, l = t & 63, lr = l & 15, lk = l >> 4;
  const int row_o = t & 15;
  const int hb    = ((t >> 4) & 15) * 8;
  const bool act  = (t < 256);     // waves 0-3: state-owning threads

  // ---- persistent weight fragments (wave w: cols w*32 + ct*16 + lr, ct in {0,1}) ----
  bf16x8 w0f[2][4], w1f[2][8];
  float bias0v[2], bias1v[2], bias2v[2];
#pragma unroll
  for (int ct = 0; ct < 2; ++ct) {
    const int col = w * 32 + ct * 16 + lr;
    bias0v[ct] = b0g[col];
    bias1v[ct] = b1g[col];
    bias2v[ct] = b2g[hs * 256 + col];
    const u16* base0 = w0b + (size_t)col * 128 + lk * 8;
#pragma unroll
    for (int ks = 0; ks < 4; ++ks) w0f[ct][ks] = *(const bf16x8*)(base0 + ks * 32);
    const u16* base1 = w1b + (size_t)col * 256 + lk * 8;
#pragma unroll
    for (int ks = 0; ks < 8; ++ks) w1f[ct][ks] = *(const bf16x8*)(base1 + ks * 32);
    const u16* base2 = w2b + (size_t)(hs * 256 + col) * 256 + lk * 8;
#pragma unroll
    for (int ks = 0; ks < 8; ++ks) {
      u32x4 v = *(const u32x4*)(base2 + ks * 32);
      *(u32x4*)&w2l[(size_t)((ks * 16 + (w * 2 + ct)) * 64 + l) * 4] = v;
    }
  }

  // ---- y0 (valid for act threads; duplicates elsewhere, never stored) ----
  float yv[8];
  {
    const float* xr = x0g + (size_t)(b0r + row_o) * 32;
#pragma unroll
    for (int e = 0; e < 8; ++e) {
      float acc = l1b[hb + e];
      const float* wr = l1w + (size_t)(hb + e) * 32;
#pragma unroll
      for (int d = 0; d < 32; ++d) acc = fmaf(xr[d], wr[d], acc);
      yv[e] = acc;
    }
  }

  u32 kk[6][4];
#pragma unroll
  for (int j = 0; j < 6; ++j)
#pragma unroll
    for (int p = 0; p < 4; ++p) kk[j][p] = 0u;

  float pcb[2], pcc[2], pcd[2];
  auto ld_coeff = [&](int st) {
    if (!act) return;
    size_t gi = ((size_t)(b0r + (t >> 4)) * 511 + st) * 32 + 2 * (t & 15);
    float2 vb = *(const float2*)(cbg + gi); pcb[0] = vb.x; pcb[1] = vb.y;
    float2 vc = *(const float2*)(ccg + gi); pcc[0] = vc.x; pcc[1] = vc.y;
    float2 vd = *(const float2*)(cdg + gi); pcd[0] = vd.x; pcd[1] = vd.y;
  };
  pcb[0]=pcb[1]=pcc[0]=pcc[1]=pcd[0]=pcd[1]=0.f;
  ld_coeff(0);
  float hh_next = ts[1] - ts[0];
  // act thread's 16B of each (stage,group) slab: slice=t>>4, row=t&15
  const size_t myoff = (size_t)((t >> 4) * 64 + (t & 15) * 4);
  __syncthreads();

#pragma unroll 1
  for (int step = 0; step < NSTEPS; ++step) {
    const float hh = hh_next;
    const float cb0 = pcb[0], cb1 = pcb[1];
    const float cc0 = pcc[0], cc1 = pcc[1];
    const float cd0 = pcd[0], cd1 = pcd[1];
    if (step + 1 < NSTEPS) { ld_coeff(step + 1); hh_next = ts[step + 2] - ts[step + 1]; }
    const u32 tg = (u32)(step + 1) & 3u;              // per-step sequence tag
    const u32 tgins = (tg & 1u) | ((tg & 2u) << 15);  // bit0 + bit16

    // act threads spin until their 4 tagged words of stage sdone arrive
    auto spin_gather = [&](int sdone, u32 (&kks)[4]) {
      if (!act) return;
      const u64* p = (const u64*)(kg + (size_t)((sdone * 16 + g) * 16) * 64 + myoff);
      u64 a, b;
      for (;;) {
        a = __hip_atomic_load(p,     __ATOMIC_RELAXED, __HIP_MEMORY_SCOPE_AGENT);
        b = __hip_atomic_load(p + 1, __ATOMIC_RELAXED, __HIP_MEMORY_SCOPE_AGENT);
        u32 a0 = (u32)a, a1 = (u32)(a >> 32), b0 = (u32)b, b1 = (u32)(b >> 32);
        u32 t0 = (a0 & 1u) | ((a0 >> 15) & 2u);
        u32 t1 = (a1 & 1u) | ((a1 >> 15) & 2u);
        u32 t2 = (b0 & 1u) | ((b0 >> 15) & 2u);
        u32 t3 = (b1 & 1u) | ((b1 >> 15) & 2u);
        if (((t0 ^ tg) | (t1 ^ tg) | (t2 ^ tg) | (t3 ^ tg)) == 0u) break;
      }
      kks[0] = (u32)a; kks[1] = (u32)(a >> 32); kks[2] = (u32)b; kks[3] = (u32)(b >> 32);
    };

    auto run = [&](int s) {  // s compile-time after unroll
      if (act) {
        const float fr = CT6c[s] * hh;
        int d0 = 2 * (t & 15), rl = t >> 4;
        dxt[d0 * 17 + rl]       = cb0 + fr * (2.f * cc0 + 3.f * fr * cd0);
        dxt[(d0 + 1) * 17 + rl] = cb1 + fr * (2.f * cc1 + 3.f * fr * cd1);
        u32 yp[4];
#pragma unroll
        for (int p = 0; p < 4; ++p) {
          float v0 = yv[2 * p], v1 = yv[2 * p + 1];
          for (int j = 0; j < s; ++j) {
            const float aj = hh * AT6c[s][j];
            v0 = fmaf(aj, blo(kk[j][p]), v0);
            v1 = fmaf(aj, bhi(kk[j][p]), v1);
          }
          yp[p] = cvt_pk(v0, v1);
        }
        int boff = row_o * 256 + ((((t >> 4) & 15) * 16) ^ ((row_o & 7) << 4));
        u32x4 wv_; wv_[0] = yp[0]; wv_[1] = yp[1]; wv_[2] = yp[2]; wv_[3] = yp[3];
        *(u32x4*)((char*)ysl + boff) = wv_;
      }
      __syncthreads();

      // GEMM1 (per wave: 2 ct tiles)
      f32x4 acc[2];
#pragma unroll
      for (int ct = 0; ct < 2; ++ct) acc[ct] = f32x4{0.f, 0.f, 0.f, 0.f};
#pragma unroll
      for (int ks = 0; ks < 4; ++ks) {
        bf16x8 af = *(const bf16x8*)((char*)ysl + lr * 256 + ((ks * 64 + lk * 16) ^ ((lr & 7) << 4)));
#pragma unroll
        for (int ct = 0; ct < 2; ++ct) acc[ct] = MF(af, w0f[ct][ks], acc[ct]);
      }
#pragma unroll
      for (int ct = 0; ct < 2; ++ct) {
        int col2 = (w * 32 + ct * 16 + lr) * 2;
        int r0 = lk * 4;
        u32 p01 = cvt_pk(fsilu(acc[ct][0] + bias0v[ct]), fsilu(acc[ct][1] + bias0v[ct]));
        u32 p23 = cvt_pk(fsilu(acc[ct][2] + bias0v[ct]), fsilu(acc[ct][3] + bias0v[ct]));
        *(u16*)((char*)h1l + (r0 + 0) * 512 + (col2 ^ (((r0 + 0) & 7) << 4))) = (u16)p01;
        *(u16*)((char*)h1l + (r0 + 1) * 512 + (col2 ^ (((r0 + 1) & 7) << 4))) = (u16)(p01 >> 16);
        *(u16*)((char*)h1l + (r0 + 2) * 512 + (col2 ^ (((r0 + 2) & 7) << 4))) = (u16)p23;
        *(u16*)((char*)h1l + (r0 + 3) * 512 + (col2 ^ (((r0 + 3) & 7) << 4))) = (u16)(p23 >> 16);
      }
      __syncthreads();

      // GEMM2
#pragma unroll
      for (int ct = 0; ct < 2; ++ct) acc[ct] = f32x4{0.f, 0.f, 0.f, 0.f};
#pragma unroll
      for (int ks = 0; ks < 8; ++ks) {
        bf16x8 af = *(const bf16x8*)((char*)h1l + lr * 512 + ((ks * 64 + lk * 16) ^ ((lr & 7) << 4)));
#pragma unroll
        for (int ct = 0; ct < 2; ++ct) acc[ct] = MF(af, w1f[ct][ks], acc[ct]);
      }
#pragma unroll
      for (int ct = 0; ct < 2; ++ct) {
        int col2 = (w * 32 + ct * 16 + lr) * 2;
        int r0 = lk * 4;
        u32 p01 = cvt_pk(fsilu(acc[ct][0] + bias1v[ct]), fsilu(acc[ct][1] + bias1v[ct]));
        u32 p23 = cvt_pk(fsilu(acc[ct][2] + bias1v[ct]), fsilu(acc[ct][3] + bias1v[ct]));
        *(u16*)((char*)h2l + (r0 + 0) * 512 + (col2 ^ (((r0 + 0) & 7) << 4))) = (u16)p01;
        *(u16*)((char*)h2l + (r0 + 1) * 512 + (col2 ^ (((r0 + 1) & 7) << 4))) = (u16)(p01 >> 16);
        *(u16*)((char*)h2l + (r0 + 2) * 512 + (col2 ^ (((r0 + 2) & 7) << 4))) = (u16)p23;
        *(u16*)((char*)h2l + (r0 + 3) * 512 + (col2 ^ (((r0 + 3) & 7) << 4))) = (u16)(p23 >> 16);
      }
      __syncthreads();

      // GEMM3 (gct = w*2+ct) + tanh + dX contract; wave w produces h = hs*8 + w
#pragma unroll
      for (int ct = 0; ct < 2; ++ct) acc[ct] = f32x4{0.f, 0.f, 0.f, 0.f};
#pragma unroll
      for (int ks = 0; ks < 8; ++ks) {
        bf16x8 af = *(const bf16x8*)((char*)h2l + lr * 512 + ((ks * 64 + lk * 16) ^ ((lr & 7) << 4)));
#pragma unroll
        for (int ct = 0; ct < 2; ++ct) {
          bf16x8 bf = *(const bf16x8*)&w2l[(size_t)((ks * 16 + (w * 2 + ct)) * 64 + l) * 4];
          acc[ct] = MF(af, bf, acc[ct]);
        }
      }
      {
        float sv[4];
#pragma unroll
        for (int r = 0; r < 4; ++r) {
          int row = lk * 4 + r;
          sv[r] = ftanh(acc[0][r] + bias2v[0]) * dxt[lr * 17 + row] +
                  ftanh(acc[1][r] + bias2v[1]) * dxt[(16 + lr) * 17 + row];
        }
#pragma unroll
        for (int m = 1; m < 16; m <<= 1) {
#pragma unroll
          for (int r = 0; r < 4; ++r) sv[r] += __shfl_xor(sv[r], m, 64);
        }
        if (lr == 0) {
#pragma unroll
          for (int r = 0; r < 4; ++r)
            *((u16*)kexw + (lk * 4 + r) * 8 + w) = (u16)cvt_pk(sv[r], sv[r]);
        }
      }
      __syncthreads();
      // wave 0: tag + coalesced 256B relaxed store. Single hop — no drain, no flag.
      const size_t slab = (size_t)((s * 16 + g) * 16 + hs) * 64;
      if (t < 64) {
        u32 val = (kexw[l] & 0xFFFEFFFEu) | tgins;
        __hip_atomic_store(&kg[slab + l], val, __ATOMIC_RELAXED, __HIP_MEMORY_SCOPE_AGENT);
      }
    };

#pragma unroll
    for (int s = 0; s < 6; ++s) {
      if (s > 0) spin_gather(s - 1, kk[s - 1]);
      run(s);
    }
    spin_gather(5, kk[5]);

    // y += h * sum_j B[j] k_j (act threads hold real state)
#pragma unroll
    for (int p = 0; p < 4; ++p) {
      float v0 = yv[2 * p], v1 = yv[2 * p + 1];
#pragma unroll
      for (int j = 0; j < 6; ++j) {
        const float cj = hh * BT6c[j];
        v0 = fmaf(cj, blo(kk[j][p]), v0);
        v1 = fmaf(cj, bhi(kk[j][p]), v1);
      }
      yv[2 * p] = v0; yv[2 * p + 1] = v1;
    }
  }  // steps

  // ---- head ----
  __syncthreads();
  if (hs == 0) {
    float* yh = (float*)w2l;
    if (act) {
#pragma unroll
      for (int e = 0; e < 8; ++e) yh[row_o * 132 + hb + e] = yv[e];
    }
    __syncthreads();
    if (t < 160) {
      int r = t / 10, c = t - r * 10;
      float acc = l2b[c];
      const float* wr = l2w + (size_t)c * 128;
      for (int h2 = 0; h2 < 128; ++h2) acc = fmaf(yh[r * 132 + h2], wr[h2], acc);
      lg[r * 12 + c] = acc;
    }
    __syncthreads();
    if (t < 16) {
      float m = lg[t * 12];
#pragma unroll
      for (int c = 1; c < 10; ++c) m = fmaxf(m, lg[t * 12 + c]);
      float sum = 0.f, ex[10];
#pragma unroll
      for (int c = 0; c < 10; ++c) { ex[c] = __expf(lg[t * 12 + c] - m); sum += ex[c]; }
      float inv = 1.f / sum;
#pragma unroll
      for (int c = 0; c < 10; ++c) outp[(size_t)(b0r + t) * 10 + c] = ex[c] * inv;
    }
  }
}

extern "C" void kernel_launch(void* const* d_in, const int* in_sizes, int n_in,
                              void* d_out, int out_size, void* d_ws, size_t ws_size,
                              hipStream_t stream) {
  (void)in_sizes; (void)n_in; (void)out_size;
  if (ws_size < WS_NEED) return;

  const float* ts  = (const float*)d_in[0];
  const float* cd  = (const float*)d_in[1];
  const float* cc  = (const float*)d_in[2];
  const float* cb  = (const float*)d_in[3];
  // d_in[4] = coeff_a (unused by the reference math)
  const float* x0  = (const float*)d_in[5];
  const float* l1w = (const float*)d_in[6];
  const float* l1b = (const float*)d_in[7];
  const float* w0  = (const float*)d_in[8];
  const float* b0  = (const float*)d_in[9];
  const float* w1  = (const float*)d_in[10];
  const float* b1  = (const float*)d_in[11];
  const float* w2  = (const float*)d_in[12];
  const float* b2  = (const float*)d_in[13];
  const float* l2w = (const float*)d_in[14];
  const float* l2b = (const float*)d_in[15];

  char* ws = (char*)d_ws;
  u32* kg  = (u32*)(ws + K_OFF);
  u16* w0b = (u16*)(ws + W0_OFF);
  u16* w1b = (u16*)(ws + W1_OFF);
  u16* w2b = (u16*)(ws + W2_OFF);

  // init kg to tag=3 pattern (0x01010101): never matches any step's expected tag
  // before its first write, on every call (fresh or replayed).
  (void)hipMemsetAsync(kg, 0x01, KG_U32 * 4, stream);
  cvt_weights<<<4096, 256, 0, stream>>>(w0, w1, w2, w0b, w1b, w2b);
  cde_kernel<<<NWG, NTHR, 0, stream>>>(ts, cd, cc, cb, x0, l1w, l1b,
                                       b0, b1, b2, l2w, l2b,
                                       w0b, w1b, w2b, kg, (float*)d_out);
}